// Round 7
// baseline (1826.090 us; speedup 1.0000x reference)
//
#include <hip/hip_runtime.h>

// ---------------------------------------------------------------------------
// LSTM forecaster. R22 = 4-WAVE BLOCKS for true 2-block/CU co-residency.
// Residency law measured over R15-R21: per-SIMD arch-reg pool ~256, blocks
// placed whole: 8-wave block needs 2 waves/SIMD -> 2 blocks only at <=64
// regs (spills, R16/R17); 4-wave block needs 1 wave/SIMD -> 2 blocks fit at
// <=128 regs. R21's dual-layer jam spilled (128 acc f32 alone; FETCH 1GB).
// Structure: 512 blocks x 256 threads (4 waves) x 32 batch rows. Each wave
// covers j in {16w+nib, 16w+nib+64} (jj=0,1): acc[2][4][2] = 64 f32,
// b 16, a 8 -> ~120 regs <= 128 budget (waves_per_eu(2), proven). c-state in
// LDS; LDS ~71KB/block -> 2 blocks = 142KB < 160KB. One round, 2 independent
// barrier domains per CU: one block's cell phase overlaps the other's mma.
// Per-acc K-chunk order EXACTLY preserved -> numerics identical to R15
// (absmax must stay 0.0009765625).
// ---------------------------------------------------------------------------

typedef __attribute__((ext_vector_type(8))) short short8;   // 8 x bf16 frag
typedef __attribute__((ext_vector_type(4))) float float4v;  // 4 x f32 acc

#define MFMA16(a, b, c) __builtin_amdgcn_mfma_f32_16x16x32_bf16((a), (b), (c), 0, 0, 0)

__device__ __forceinline__ unsigned short f2bf(float x) {
    unsigned u = __builtin_bit_cast(unsigned, x);
    unsigned r = (u + 0x7FFFu + ((u >> 16) & 1u)) >> 16;  // RNE
    return (unsigned short)r;
}
__device__ __forceinline__ float bf2f(unsigned short b) {
    unsigned u = ((unsigned)b) << 16;
    return __builtin_bit_cast(float, u);
}

#if __has_builtin(__builtin_amdgcn_exp2f)
__device__ __forceinline__ float vexp2(float x) { return __builtin_amdgcn_exp2f(x); }
#else
__device__ __forceinline__ float vexp2(float x) { return exp2f(x); }
#endif
#if __has_builtin(__builtin_amdgcn_rcpf)
__device__ __forceinline__ float vrcp(float x) { return __builtin_amdgcn_rcpf(x); }
#else
__device__ __forceinline__ float vrcp(float x) { return 1.0f / x; }
#endif

__device__ __forceinline__ float sigm(float x) {
    return vrcp(1.0f + vexp2(x * -1.442695040888963f));
}
__device__ __forceinline__ float tanh_(float x) {
    return 1.0f - 2.0f * vrcp(1.0f + vexp2(x * 2.885390081777927f));
}

// ---------------------------------------------------------------------------
// prep kernel: fp32 weights -> bf16, concatenated per-layer [Wih | Whh],
// Wih0 padded 10->32; biases summed AND transposed to [set][j][q] float4;
// decoder-y weights transposed to [j][8].
// ws layout: We0[512][160] | We1[512][256] | Wd0[512][128] | Wd1[512][256]
//            (bf16, 819200 B) | bsT[4][128][4] f32 (8 KB) | wyT[128][8] f32 (4 KB)
// ---------------------------------------------------------------------------
__global__ void prep_kernel(const float* __restrict__ eWih0, const float* __restrict__ eWhh0,
                            const float* __restrict__ ebih0, const float* __restrict__ ebhh0,
                            const float* __restrict__ eWih1, const float* __restrict__ eWhh1,
                            const float* __restrict__ ebih1, const float* __restrict__ ebhh1,
                            const float* __restrict__ dWih0, const float* __restrict__ dWhh0,
                            const float* __restrict__ dbih0, const float* __restrict__ dbhh0,
                            const float* __restrict__ dWih1, const float* __restrict__ dWhh1,
                            const float* __restrict__ dbih1, const float* __restrict__ dbhh1,
                            void* __restrict__ ws)
{
    int i = blockIdx.x * 256 + threadIdx.x;
    short* We0 = (short*)ws;
    short* We1 = We0 + 512 * 160;
    short* Wd0 = We1 + 512 * 256;
    short* Wd1 = Wd0 + 512 * 128;
    float* bsT = (float*)((char*)ws + 819200);
    float* wyT = bsT + 2048;
    const int N0 = 512 * 160, N1 = 512 * 256, N2 = 512 * 128, N3 = 512 * 256;
    if (i < N0) {
        int n = i / 160, k = i - n * 160;
        float v = (k < 32) ? (k < 10 ? eWih0[n * 10 + k] : 0.0f) : eWhh0[n * 128 + (k - 32)];
        We0[i] = (short)f2bf(v);
    } else if (i < N0 + N1) {
        int ii = i - N0, n = ii >> 8, k = ii & 255;
        float v = (k < 128) ? eWih1[n * 128 + k] : eWhh1[n * 128 + (k - 128)];
        We1[ii] = (short)f2bf(v);
    } else if (i < N0 + N1 + N2) {
        int ii = i - (N0 + N1);
        Wd0[ii] = (short)f2bf(dWhh0[ii]);
    } else if (i < N0 + N1 + N2 + N3) {
        int ii = i - (N0 + N1 + N2), n = ii >> 8, k = ii & 255;
        float v = (k < 128) ? dWih1[n * 128 + k] : dWhh1[n * 128 + (k - 128)];
        Wd1[ii] = (short)f2bf(v);
    } else if (i < N0 + N1 + N2 + N3 + 2048) {
        int ii = i - (N0 + N1 + N2 + N3);
        int set = ii >> 9, r = ii & 511, j = r >> 2, q = r & 3;
        int g = q * 128 + j;
        float v = (set == 0) ? ebih0[g] + ebhh0[g]
                : (set == 1) ? ebih1[g] + ebhh1[g]
                : (set == 2) ? dbih0[g] + dbhh0[g]
                             : dbih1[g] + dbhh1[g];
        bsT[ii] = v;
    } else if (i < N0 + N1 + N2 + N3 + 2048 + 1024) {
        int ii = i - (N0 + N1 + N2 + N3 + 2048);
        int j = ii >> 3, e = ii & 7, q = e >> 1, cc = e & 1;
        wyT[ii] = dWih0[(q * 128 + j) * 2 + cc];
    }
}

// ---------------------------------------------------------------------------
// main kernel (per block: 32 batch rows, 4 waves)
// LDS h-buffers ping-pong [2] x (32 rows x 16 chunks): slot = m*16+(kc^(m&15))
// xbuf ping-pong [2] x (32 rows x 4 chunks): slot = m*4+(kc^(m&3))
// c-state in LDS: cbuf[m*132 + j] (2-way bank access = free)
// Wave w in [0,4): j-halves jj=0,1 -> j = 16w+nib + 64*jj;
// n-tiles {w+4jj+8q}; m-tiles {0,1}; acc[jj][q][mt] = 64 f32.
// ---------------------------------------------------------------------------

// b[q] = W row (q*128 + jhalf-base), 4 rows spaced 128*RB bytes
template <int RB>
__device__ __forceinline__ void ldb4q(const char* __restrict__ wb, unsigned base,
                                      int koff, short8 (&b)[4])
{
    const char* pb = wb + base + koff;
    b[0] = *(const short8*)(pb);
    b[1] = *(const short8*)(pb + 128 * RB);
    b[2] = *(const short8*)(pb + 256 * RB);
    b[3] = *(const short8*)(pb + 384 * RB);
}

// 8 MFMAs: acc[q][mt] += a_mt x b[q]
__device__ __forceinline__ void qmma2(float4v (&acc)[4][2], short8 a0, short8 a1,
                                      const short8 (&b)[4])
{
#pragma unroll
    for (int q = 0; q < 4; ++q) {
        acc[q][0] = MFMA16(a0, b[q], acc[q][0]);
        acc[q][1] = MFMA16(a1, b[q], acc[q][1]);
    }
}

// elementwise LSTM cell update for ONE j-half; c-state in LDS
template <bool DEC0>
__device__ __forceinline__ void cell_upd(float4v (&acc)[4][2], int j,
                                         const float* __restrict__ bsTset,
                                         float* __restrict__ cbase,
                                         unsigned short* __restrict__ hdst,
                                         const float* __restrict__ ybuf,
                                         const float* __restrict__ wyT,
                                         int quad)
{
    float4v bv = *(const float4v*)(bsTset + j * 4);
    float4v wy0 = {0, 0, 0, 0}, wy1 = {0, 0, 0, 0};
    if (DEC0) {
        wy0 = *(const float4v*)(wyT + j * 8);
        wy1 = *(const float4v*)(wyT + j * 8 + 4);
    }
    int kc = j >> 3;
    int jl = j & 7;
#pragma unroll
    for (int mt = 0; mt < 2; ++mt) {
#pragma unroll
        for (int r = 0; r < 4; ++r) {
            float gi = acc[0][mt][r] + bv[0];
            float gf = acc[1][mt][r] + bv[1];
            float gg = acc[2][mt][r] + bv[2];
            float go = acc[3][mt][r] + bv[3];
            int m = mt * 16 + quad * 4 + r;
            if (DEC0) {
                float y0 = ybuf[2 * m], y1 = ybuf[2 * m + 1];
                gi += y0 * wy0[0] + y1 * wy0[1];
                gf += y0 * wy0[2] + y1 * wy0[3];
                gg += y0 * wy1[0] + y1 * wy1[1];
                go += y0 * wy1[2] + y1 * wy1[3];
            }
            float si = sigm(gi);
            float sf = sigm(gf);
            float tg = tanh_(gg);
            float so = sigm(go);
            float* cp = cbase + (m * 132 + j);
            float c = sf * (*cp) + si * tg;
            *cp = c;
            float h = so * tanh_(c);
            int slot = m * 16 + (kc ^ (m & 15));
            hdst[slot * 8 + jl] = f2bf(h);
        }
    }
}

__global__ void __attribute__((amdgpu_flat_work_group_size(256, 256), amdgpu_waves_per_eu(2)))
lstm_main(
    const float* __restrict__ hist,
    const float* __restrict__ headW, const float* __restrict__ headB,
    const int* __restrict__ futlen, const void* __restrict__ ws,
    float* __restrict__ out)
{
    __shared__ short8 h0buf[2][512];   // ping-pong, 32 rows x 16 chunks (16 KB)
    __shared__ short8 h1buf[2][512];   // 16 KB
    __shared__ short8 xbuf[2][128];    // ping-pong, 32 rows x 4 chunks (4 KB)
    __shared__ float ybuf[64];         // [32][2]
    __shared__ float cbuf0[32 * 132];  // c-state layer 0 (16.9 KB)
    __shared__ float cbuf1[32 * 132];  // c-state layer 1 (16.9 KB)

    const char* wsb = (const char*)ws;
    const char* We0 = wsb;                       // rows of 320 B
    const char* We1 = wsb + 512 * 160 * 2;       // rows of 512 B
    const char* Wd0 = We1 + 512 * 256 * 2;       // rows of 256 B
    const char* Wd1 = Wd0 + 512 * 128 * 2;       // rows of 512 B
    const float* bsT = (const float*)(wsb + 819200);
    const float* wyT = bsT + 2048;

    const int tid = threadIdx.x;
    const int w = tid >> 6;          // wave in [0,4)
    const int lane = tid & 63;
    const int quad = lane >> 4;
    const int nib = lane & 15;
    const int b0 = blockIdx.x * 32;
    const int TFUT = *futlen;
    const int j0 = 16 * w + nib;     // first j-half
    const int j1 = j0 + 64;          // second j-half

    // zero-init LDS state. h1: BOTH parities (pipelined L1(0) reads h1[1]).
    h0buf[0][tid] = (short8)0;
    h0buf[0][256 + tid] = (short8)0;
    h1buf[0][tid] = (short8)0;
    h1buf[0][256 + tid] = (short8)0;
    h1buf[1][tid] = (short8)0;
    h1buf[1][256 + tid] = (short8)0;
    ((short8*)xbuf)[tid] = (short8)0;  // 256 slots = both parities
    if (tid < 64) ybuf[tid] = 0.0f;
    for (int i = tid; i < 32 * 132; i += 256) {
        cbuf0[i] = 0.0f;
        cbuf1[i] = 0.0f;
    }
    __syncthreads();  // zero-init visible before initial staging writes

    // stage x(t=0) into xbuf[0]
    if (tid < 64) {
        int m = tid & 31, part = tid >> 5;
        const float* hp = hist + ((size_t)((b0 + m) * 20 + 0)) * 10;
        float v[8];
        if (part == 0) {
#pragma unroll
            for (int i = 0; i < 8; ++i) v[i] = hp[i];
        } else {
            v[0] = hp[8]; v[1] = hp[9];
#pragma unroll
            for (int i = 2; i < 8; ++i) v[i] = 0.0f;
        }
        short8 pk;
#pragma unroll
        for (int i = 0; i < 8; ++i) pk[i] = (short)f2bf(v[i]);
        xbuf[0][m * 4 + (part ^ (m & 3))] = pk;
    }

    // per-jj base byte offsets (q-stride is the compile-time 128*RB in ldb4q)
    unsigned e0b[2], e1b[2], d0b[2];
#pragma unroll
    for (int jj = 0; jj < 2; ++jj) {
        unsigned rr = 64u * jj + 16u * w + nib;
        e0b[jj] = rr * 320u + quad * 16u;
        e1b[jj] = rr * 512u + quad * 16u;
        d0b[jj] = rr * 256u + quad * 16u;
    }
    int p0 = 0, p1 = 0, px = 0;
    __syncthreads();

    // ================= ENCODER: 21 layer-pipelined windows =================
    // window wdw: L0(wdw) [wdw<20] + L1(wdw-1) [wdw>=1]; ONE barrier.
#pragma unroll 1
    for (int wdw = 0; wdw < 21; ++wdw) {
        if (wdw < 20) {
            // ---- L0(wdw): gates = x@Wih0^T + h0@Whh0^T; fused cell ----
            float4v acc[2][4][2];
#pragma unroll
            for (int jj = 0; jj < 2; ++jj)
#pragma unroll
                for (int q = 0; q < 4; ++q)
#pragma unroll
                    for (int mt = 0; mt < 2; ++mt) acc[jj][q][mt] = (float4v){0.f, 0.f, 0.f, 0.f};
            // x part (k 0..31) from xbuf[px]
            {
                const short8* xb = xbuf[px];
                int sxx = (quad ^ (nib & 3)) + nib * 4;
                short8 a0 = xb[sxx];
                short8 a1 = xb[64 + sxx];
#pragma unroll
                for (int jj = 0; jj < 2; ++jj) {
                    short8 b[4];
                    ldb4q<320>(We0, e0b[jj], 0, b);
                    qmma2(acc[jj], a0, a1, b);
                }
            }
            // h part (W k 32..159, bytes 64..) from h0buf[p0]
#pragma unroll
            for (int kk = 0; kk < 4; ++kk) {
                int sx = ((kk * 4 + quad) ^ nib) + nib * 16;
                short8 a0 = h0buf[p0][sx];
                short8 a1 = h0buf[p0][256 + sx];
#pragma unroll
                for (int jj = 0; jj < 2; ++jj) {
                    short8 b[4];
                    ldb4q<320>(We0, e0b[jj], 64 + kk * 64, b);
                    qmma2(acc[jj], a0, a1, b);
                }
            }
            unsigned short* hdst = (unsigned short*)h0buf[p0 ^ 1];
            cell_upd<false>(acc[0], j0, bsT + 0 * 512, cbuf0, hdst, nullptr, nullptr, quad);
            cell_upd<false>(acc[1], j1, bsT + 0 * 512, cbuf0, hdst, nullptr, nullptr, quad);
        }

        // stage x(wdw+1) into xbuf[px^1] (consumed next window after barrier)
        if (tid < 64 && wdw < 19) {
            int m = tid & 31, part = tid >> 5;
            const float* hp = hist + ((size_t)((b0 + m) * 20 + (wdw + 1))) * 10;
            float v[8];
            if (part == 0) {
#pragma unroll
                for (int i = 0; i < 8; ++i) v[i] = hp[i];
            } else {
                v[0] = hp[8]; v[1] = hp[9];
#pragma unroll
                for (int i = 2; i < 8; ++i) v[i] = 0.0f;
            }
            short8 pk;
#pragma unroll
            for (int i = 0; i < 8; ++i) pk[i] = (short)f2bf(v[i]);
            xbuf[px ^ 1][m * 4 + (part ^ (m & 3))] = pk;
        }

        if (wdw >= 1) {
            // ---- L1(wdw-1): gates = h0(wdw-1)@Wih1^T + h1(wdw-2)@Whh1^T ----
            float4v acc[2][4][2];
#pragma unroll
            for (int jj = 0; jj < 2; ++jj)
#pragma unroll
                for (int q = 0; q < 4; ++q)
#pragma unroll
                    for (int mt = 0; mt < 2; ++mt) acc[jj][q][mt] = (float4v){0.f, 0.f, 0.f, 0.f};
            // h0 chunks (pre-window h0 = h0buf[p0])
#pragma unroll
            for (int kk = 0; kk < 4; ++kk) {
                int sx = ((kk * 4 + quad) ^ nib) + nib * 16;
                short8 a0 = h0buf[p0][sx];
                short8 a1 = h0buf[p0][256 + sx];
#pragma unroll
                for (int jj = 0; jj < 2; ++jj) {
                    short8 b[4];
                    ldb4q<512>(We1, e1b[jj], kk * 64, b);
                    qmma2(acc[jj], a0, a1, b);
                }
            }
            // h1 chunks
#pragma unroll
            for (int kk = 0; kk < 4; ++kk) {
                int sx = ((kk * 4 + quad) ^ nib) + nib * 16;
                short8 a0 = h1buf[p1][sx];
                short8 a1 = h1buf[p1][256 + sx];
#pragma unroll
                for (int jj = 0; jj < 2; ++jj) {
                    short8 b[4];
                    ldb4q<512>(We1, e1b[jj], 256 + kk * 64, b);
                    qmma2(acc[jj], a0, a1, b);
                }
            }
            unsigned short* hdst = (unsigned short*)h1buf[p1 ^ 1];
            cell_upd<false>(acc[0], j0, bsT + 1 * 512, cbuf1, hdst, nullptr, nullptr, quad);
            cell_upd<false>(acc[1], j1, bsT + 1 * 512, cbuf1, hdst, nullptr, nullptr, quad);
        }
        __syncthreads();
        p0 ^= 1; p1 ^= 1; px ^= 1;
    }

    // Parity ledger: h0(19) -> h0buf[0]; h1(19) -> h1buf[1].
    p0 = 0;
    p1 = 1;

    // ================= DECODER =================
    // Per window t: [head(t-1) || mma0(t)] -> A -> cell0(t) -> B ->
    //               mma1(t)+cell1(t) -> C.   Epilogue: head(TFUT-1).
#pragma unroll 1
    for (int t = 0; t < TFUT; ++t) {
        // ---- head(t-1) (tid<64, hidden behind mma0) ----
        if (tid < 64 && t >= 1) {
            int m = tid & 31, jj = tid >> 5;
            const short8* hb = h1buf[p1];
            const float4v* hw = (const float4v*)(headW + jj * 128);
            float dot = headB[jj];
            int mk = m & 15;
#pragma unroll
            for (int kc = 0; kc < 16; ++kc) {
                short8 ch = hb[m * 16 + (kc ^ mk)];
                float4v w0 = hw[kc * 2], w1 = hw[kc * 2 + 1];
                dot += bf2f((unsigned short)ch[0]) * w0[0];
                dot += bf2f((unsigned short)ch[1]) * w0[1];
                dot += bf2f((unsigned short)ch[2]) * w0[2];
                dot += bf2f((unsigned short)ch[3]) * w0[3];
                dot += bf2f((unsigned short)ch[4]) * w1[0];
                dot += bf2f((unsigned short)ch[5]) * w1[1];
                dot += bf2f((unsigned short)ch[6]) * w1[2];
                dot += bf2f((unsigned short)ch[7]) * w1[3];
            }
            ybuf[2 * m + jj] = dot;
            out[((size_t)(b0 + m) * TFUT + (t - 1)) * 2 + jj] = dot;
        }

        // ---- dec layer 0: mma0 -> A -> cell0 (uses y(t-1)) ----
        {
            float4v acc[2][4][2];
#pragma unroll
            for (int jj = 0; jj < 2; ++jj)
#pragma unroll
                for (int q = 0; q < 4; ++q)
#pragma unroll
                    for (int mt = 0; mt < 2; ++mt) acc[jj][q][mt] = (float4v){0.f, 0.f, 0.f, 0.f};
#pragma unroll
            for (int kk = 0; kk < 4; ++kk) {
                int sx = ((kk * 4 + quad) ^ nib) + nib * 16;
                short8 a0 = h0buf[p0][sx];
                short8 a1 = h0buf[p0][256 + sx];
#pragma unroll
                for (int jj = 0; jj < 2; ++jj) {
                    short8 b[4];
                    ldb4q<256>(Wd0, d0b[jj], kk * 64, b);
                    qmma2(acc[jj], a0, a1, b);
                }
            }
            __syncthreads();  // A: ybuf(t-1) visible
            unsigned short* hdst = (unsigned short*)h0buf[p0 ^ 1];
            cell_upd<true>(acc[0], j0, bsT + 2 * 512, cbuf0, hdst, ybuf, wyT, quad);
            cell_upd<true>(acc[1], j1, bsT + 2 * 512, cbuf0, hdst, ybuf, wyT, quad);
        }
        __syncthreads();  // B: h0 new visible

        // ---- dec layer 1; fused cell ----
        {
            float4v acc[2][4][2];
#pragma unroll
            for (int jj = 0; jj < 2; ++jj)
#pragma unroll
                for (int q = 0; q < 4; ++q)
#pragma unroll
                    for (int mt = 0; mt < 2; ++mt) acc[jj][q][mt] = (float4v){0.f, 0.f, 0.f, 0.f};
            // new h0 chunks
#pragma unroll
            for (int kk = 0; kk < 4; ++kk) {
                int sx = ((kk * 4 + quad) ^ nib) + nib * 16;
                short8 a0 = h0buf[p0 ^ 1][sx];
                short8 a1 = h0buf[p0 ^ 1][256 + sx];
#pragma unroll
                for (int jj = 0; jj < 2; ++jj) {
                    short8 b[4];
                    ldb4q<512>(Wd1, e1b[jj], kk * 64, b);
                    qmma2(acc[jj], a0, a1, b);
                }
            }
            // old h1 chunks
#pragma unroll
            for (int kk = 0; kk < 4; ++kk) {
                int sx = ((kk * 4 + quad) ^ nib) + nib * 16;
                short8 a0 = h1buf[p1][sx];
                short8 a1 = h1buf[p1][256 + sx];
#pragma unroll
                for (int jj = 0; jj < 2; ++jj) {
                    short8 b[4];
                    ldb4q<512>(Wd1, e1b[jj], 256 + kk * 64, b);
                    qmma2(acc[jj], a0, a1, b);
                }
            }
            unsigned short* hdst = (unsigned short*)h1buf[p1 ^ 1];
            cell_upd<false>(acc[0], j0, bsT + 3 * 512, cbuf1, hdst, nullptr, nullptr, quad);
            cell_upd<false>(acc[1], j1, bsT + 3 * 512, cbuf1, hdst, nullptr, nullptr, quad);
        }
        __syncthreads();  // C: h1 new visible (next window's head reads it)
        p0 ^= 1; p1 ^= 1;
    }

    // ---- epilogue: head(TFUT-1) ----
    if (tid < 64) {
        int m = tid & 31, jj = tid >> 5;
        const short8* hb = h1buf[p1];
        const float4v* hw = (const float4v*)(headW + jj * 128);
        float dot = headB[jj];
        int mk = m & 15;
#pragma unroll
        for (int kc = 0; kc < 16; ++kc) {
            short8 ch = hb[m * 16 + (kc ^ mk)];
            float4v w0 = hw[kc * 2], w1 = hw[kc * 2 + 1];
            dot += bf2f((unsigned short)ch[0]) * w0[0];
            dot += bf2f((unsigned short)ch[1]) * w0[1];
            dot += bf2f((unsigned short)ch[2]) * w0[2];
            dot += bf2f((unsigned short)ch[3]) * w0[3];
            dot += bf2f((unsigned short)ch[4]) * w1[0];
            dot += bf2f((unsigned short)ch[5]) * w1[1];
            dot += bf2f((unsigned short)ch[6]) * w1[2];
            dot += bf2f((unsigned short)ch[7]) * w1[3];
        }
        out[((size_t)(b0 + m) * TFUT + (TFUT - 1)) * 2 + jj] = dot;
    }
}

extern "C" void kernel_launch(void* const* d_in, const int* in_sizes, int n_in,
                              void* d_out, int out_size, void* d_ws, size_t ws_size,
                              hipStream_t stream)
{
    const float* hist   = (const float*)d_in[0];
    const float* eWih0  = (const float*)d_in[1];
    const float* eWhh0  = (const float*)d_in[2];
    const float* ebih0  = (const float*)d_in[3];
    const float* ebhh0  = (const float*)d_in[4];
    const float* eWih1  = (const float*)d_in[5];
    const float* eWhh1  = (const float*)d_in[6];
    const float* ebih1  = (const float*)d_in[7];
    const float* ebhh1  = (const float*)d_in[8];
    const float* dWih0  = (const float*)d_in[9];
    const float* dWhh0  = (const float*)d_in[10];
    const float* dbih0  = (const float*)d_in[11];
    const float* dbhh0  = (const float*)d_in[12];
    const float* dWih1  = (const float*)d_in[13];
    const float* dWhh1  = (const float*)d_in[14];
    const float* dbih1  = (const float*)d_in[15];
    const float* dbhh1  = (const float*)d_in[16];
    const float* headW  = (const float*)d_in[17];
    const float* headB  = (const float*)d_in[18];
    const int*   futlen = (const int*)d_in[19];

    // weights 409600 bf16 + bsT 2048 f32 + wyT 1024 f32 -> 412672 work items
    prep_kernel<<<1612, 256, 0, stream>>>(eWih0, eWhh0, ebih0, ebhh0,
                                          eWih1, eWhh1, ebih1, ebhh1,
                                          dWih0, dWhh0, dbih0, dbhh0,
                                          dWih1, dWhh1, dbih1, dbhh1, d_ws);

    lstm_main<<<512, 256, 0, stream>>>(hist, headW, headB, futlen,
                                       d_ws, (float*)d_out);
}

// Round 8
// 1166.476 us; speedup vs baseline: 1.5655x; 1.5655x over previous
//
#include <hip/hip_runtime.h>

// ---------------------------------------------------------------------------
// LSTM forecaster. R23 = R22 geometry (512 x 4-wave blocks, 2 barrier
// domains per CU) with SEQUENTIAL-jj to kill the spill. R22 kept both
// j-halves' acc + cell state live -> 128-reg cap -> 3.3GB scratch. Now each
// window-layer does jj=0 (mma->cell) then jj=1 (mma->cell): live acc 32 f32,
// + R18's proven depth-1 b-prefetch (~105 regs, R18 profile measured 116
// no-spill). Cross-jj hazard-free: cell writes parity p^1, mma reads p.
// Residency: 512 blocks x 4 waves = 2048 waves = chip capacity at 2/SIMD;
// 4-wave blocks -> 2 independent blocks per CU -> one block's cell phase
// (VALU/trans) overlaps the other's mma (MFMA) -- the R16-R21 target.
// LDS ~71KB/block -> 2 blocks = 142KB < 160KB. Per-acc K-chunk order EXACTLY
// preserved -> numerics identical to R15 (absmax must stay 0.0009765625).
// ---------------------------------------------------------------------------

typedef __attribute__((ext_vector_type(8))) short short8;   // 8 x bf16 frag
typedef __attribute__((ext_vector_type(4))) float float4v;  // 4 x f32 acc

#define MFMA16(a, b, c) __builtin_amdgcn_mfma_f32_16x16x32_bf16((a), (b), (c), 0, 0, 0)

__device__ __forceinline__ unsigned short f2bf(float x) {
    unsigned u = __builtin_bit_cast(unsigned, x);
    unsigned r = (u + 0x7FFFu + ((u >> 16) & 1u)) >> 16;  // RNE
    return (unsigned short)r;
}
__device__ __forceinline__ float bf2f(unsigned short b) {
    unsigned u = ((unsigned)b) << 16;
    return __builtin_bit_cast(float, u);
}

#if __has_builtin(__builtin_amdgcn_exp2f)
__device__ __forceinline__ float vexp2(float x) { return __builtin_amdgcn_exp2f(x); }
#else
__device__ __forceinline__ float vexp2(float x) { return exp2f(x); }
#endif
#if __has_builtin(__builtin_amdgcn_rcpf)
__device__ __forceinline__ float vrcp(float x) { return __builtin_amdgcn_rcpf(x); }
#else
__device__ __forceinline__ float vrcp(float x) { return 1.0f / x; }
#endif

__device__ __forceinline__ float sigm(float x) {
    return vrcp(1.0f + vexp2(x * -1.442695040888963f));
}
__device__ __forceinline__ float tanh_(float x) {
    return 1.0f - 2.0f * vrcp(1.0f + vexp2(x * 2.885390081777927f));
}

// ---------------------------------------------------------------------------
// prep kernel: fp32 weights -> bf16, concatenated per-layer [Wih | Whh],
// Wih0 padded 10->32; biases summed AND transposed to [set][j][q] float4;
// decoder-y weights transposed to [j][8].
// ws layout: We0[512][160] | We1[512][256] | Wd0[512][128] | Wd1[512][256]
//            (bf16, 819200 B) | bsT[4][128][4] f32 (8 KB) | wyT[128][8] f32 (4 KB)
// ---------------------------------------------------------------------------
__global__ void prep_kernel(const float* __restrict__ eWih0, const float* __restrict__ eWhh0,
                            const float* __restrict__ ebih0, const float* __restrict__ ebhh0,
                            const float* __restrict__ eWih1, const float* __restrict__ eWhh1,
                            const float* __restrict__ ebih1, const float* __restrict__ ebhh1,
                            const float* __restrict__ dWih0, const float* __restrict__ dWhh0,
                            const float* __restrict__ dbih0, const float* __restrict__ dbhh0,
                            const float* __restrict__ dWih1, const float* __restrict__ dWhh1,
                            const float* __restrict__ dbih1, const float* __restrict__ dbhh1,
                            void* __restrict__ ws)
{
    int i = blockIdx.x * 256 + threadIdx.x;
    short* We0 = (short*)ws;
    short* We1 = We0 + 512 * 160;
    short* Wd0 = We1 + 512 * 256;
    short* Wd1 = Wd0 + 512 * 128;
    float* bsT = (float*)((char*)ws + 819200);
    float* wyT = bsT + 2048;
    const int N0 = 512 * 160, N1 = 512 * 256, N2 = 512 * 128, N3 = 512 * 256;
    if (i < N0) {
        int n = i / 160, k = i - n * 160;
        float v = (k < 32) ? (k < 10 ? eWih0[n * 10 + k] : 0.0f) : eWhh0[n * 128 + (k - 32)];
        We0[i] = (short)f2bf(v);
    } else if (i < N0 + N1) {
        int ii = i - N0, n = ii >> 8, k = ii & 255;
        float v = (k < 128) ? eWih1[n * 128 + k] : eWhh1[n * 128 + (k - 128)];
        We1[ii] = (short)f2bf(v);
    } else if (i < N0 + N1 + N2) {
        int ii = i - (N0 + N1);
        Wd0[ii] = (short)f2bf(dWhh0[ii]);
    } else if (i < N0 + N1 + N2 + N3) {
        int ii = i - (N0 + N1 + N2), n = ii >> 8, k = ii & 255;
        float v = (k < 128) ? dWih1[n * 128 + k] : dWhh1[n * 128 + (k - 128)];
        Wd1[ii] = (short)f2bf(v);
    } else if (i < N0 + N1 + N2 + N3 + 2048) {
        int ii = i - (N0 + N1 + N2 + N3);
        int set = ii >> 9, r = ii & 511, j = r >> 2, q = r & 3;
        int g = q * 128 + j;
        float v = (set == 0) ? ebih0[g] + ebhh0[g]
                : (set == 1) ? ebih1[g] + ebhh1[g]
                : (set == 2) ? dbih0[g] + dbhh0[g]
                             : dbih1[g] + dbhh1[g];
        bsT[ii] = v;
    } else if (i < N0 + N1 + N2 + N3 + 2048 + 1024) {
        int ii = i - (N0 + N1 + N2 + N3 + 2048);
        int j = ii >> 3, e = ii & 7, q = e >> 1, cc = e & 1;
        wyT[ii] = dWih0[(q * 128 + j) * 2 + cc];
    }
}

// ---------------------------------------------------------------------------
// main kernel (per block: 32 batch rows, 4 waves)
// LDS h-buffers ping-pong [2] x (32 rows x 16 chunks): slot = m*16+(kc^(m&15))
// xbuf ping-pong [2] x (32 rows x 4 chunks): slot = m*4+(kc^(m&3))
// c-state in LDS: cbuf[m*132 + j] (2-way bank access = free)
// Wave w in [0,4): j-halves jj=0,1 PROCESSED SEQUENTIALLY ->
// j = 16w+nib + 64*jj; n-tiles {w+4jj+8q}; m-tiles {0,1}; live acc 32 f32.
// ---------------------------------------------------------------------------

// b[q] = W row (q*128 + jhalf-base), 4 rows spaced 128*RB bytes
template <int RB>
__device__ __forceinline__ void ldb4q(const char* __restrict__ wb, unsigned base,
                                      int koff, short8 (&b)[4])
{
    const char* pb = wb + base + koff;
    b[0] = *(const short8*)(pb);
    b[1] = *(const short8*)(pb + 128 * RB);
    b[2] = *(const short8*)(pb + 256 * RB);
    b[3] = *(const short8*)(pb + 384 * RB);
}

// rolled K-loop with depth-1 b-prefetch: acc[q][mt] += a_mt x b[q]
template <int RB, int NKT>
__device__ __forceinline__ void mma_seq(float4v (&acc)[4][2], const short8* __restrict__ hb,
                                        const char* __restrict__ wb, unsigned base,
                                        int koff, int nib, int quad)
{
    short8 b0, b1, b2, b3;
    {
        short8 bb[4];
        ldb4q<RB>(wb, base, koff, bb);
        b0 = bb[0]; b1 = bb[1]; b2 = bb[2]; b3 = bb[3];
    }
#pragma unroll 1
    for (int kk = 0; kk < NKT; ++kk) {
        short8 n0 = b0, n1 = b1, n2 = b2, n3 = b3;
        if (kk + 1 < NKT) {
            short8 nb[4];
            ldb4q<RB>(wb, base, koff + (kk + 1) * 64, nb);
            n0 = nb[0]; n1 = nb[1]; n2 = nb[2]; n3 = nb[3];
        }
        int sx = ((kk * 4 + quad) ^ nib) + nib * 16;
        short8 a0 = hb[sx];
        short8 a1 = hb[256 + sx];
        acc[0][0] = MFMA16(a0, b0, acc[0][0]);
        acc[0][1] = MFMA16(a1, b0, acc[0][1]);
        acc[1][0] = MFMA16(a0, b1, acc[1][0]);
        acc[1][1] = MFMA16(a1, b1, acc[1][1]);
        acc[2][0] = MFMA16(a0, b2, acc[2][0]);
        acc[2][1] = MFMA16(a1, b2, acc[2][1]);
        acc[3][0] = MFMA16(a0, b3, acc[3][0]);
        acc[3][1] = MFMA16(a1, b3, acc[3][1]);
        b0 = n0; b1 = n1; b2 = n2; b3 = n3;
    }
}

// elementwise LSTM cell update for ONE j-half; c-state in LDS
template <bool DEC0>
__device__ __forceinline__ void cell_upd(float4v (&acc)[4][2], int j,
                                         const float* __restrict__ bsTset,
                                         float* __restrict__ cbase,
                                         unsigned short* __restrict__ hdst,
                                         const float* __restrict__ ybuf,
                                         const float* __restrict__ wyT,
                                         int quad)
{
    float4v bv = *(const float4v*)(bsTset + j * 4);
    float4v wy0 = {0, 0, 0, 0}, wy1 = {0, 0, 0, 0};
    if (DEC0) {
        wy0 = *(const float4v*)(wyT + j * 8);
        wy1 = *(const float4v*)(wyT + j * 8 + 4);
    }
    int kc = j >> 3;
    int jl = j & 7;
#pragma unroll
    for (int mt = 0; mt < 2; ++mt) {
#pragma unroll
        for (int r = 0; r < 4; ++r) {
            float gi = acc[0][mt][r] + bv[0];
            float gf = acc[1][mt][r] + bv[1];
            float gg = acc[2][mt][r] + bv[2];
            float go = acc[3][mt][r] + bv[3];
            int m = mt * 16 + quad * 4 + r;
            if (DEC0) {
                float y0 = ybuf[2 * m], y1 = ybuf[2 * m + 1];
                gi += y0 * wy0[0] + y1 * wy0[1];
                gf += y0 * wy0[2] + y1 * wy0[3];
                gg += y0 * wy1[0] + y1 * wy1[1];
                go += y0 * wy1[2] + y1 * wy1[3];
            }
            float si = sigm(gi);
            float sf = sigm(gf);
            float tg = tanh_(gg);
            float so = sigm(go);
            float* cp = cbase + (m * 132 + j);
            float c = sf * (*cp) + si * tg;
            *cp = c;
            float h = so * tanh_(c);
            int slot = m * 16 + (kc ^ (m & 15));
            hdst[slot * 8 + jl] = f2bf(h);
        }
    }
}

__global__ void __attribute__((amdgpu_flat_work_group_size(256, 256), amdgpu_waves_per_eu(2)))
lstm_main(
    const float* __restrict__ hist,
    const float* __restrict__ headW, const float* __restrict__ headB,
    const int* __restrict__ futlen, const void* __restrict__ ws,
    float* __restrict__ out)
{
    __shared__ short8 h0buf[2][512];   // ping-pong, 32 rows x 16 chunks (16 KB)
    __shared__ short8 h1buf[2][512];   // 16 KB
    __shared__ short8 xbuf[2][128];    // ping-pong, 32 rows x 4 chunks (4 KB)
    __shared__ float ybuf[64];         // [32][2]
    __shared__ float cbuf0[32 * 132];  // c-state layer 0 (16.9 KB)
    __shared__ float cbuf1[32 * 132];  // c-state layer 1 (16.9 KB)

    const char* wsb = (const char*)ws;
    const char* We0 = wsb;                       // rows of 320 B
    const char* We1 = wsb + 512 * 160 * 2;       // rows of 512 B
    const char* Wd0 = We1 + 512 * 256 * 2;       // rows of 256 B
    const char* Wd1 = Wd0 + 512 * 128 * 2;       // rows of 512 B
    const float* bsT = (const float*)(wsb + 819200);
    const float* wyT = bsT + 2048;

    const int tid = threadIdx.x;
    const int w = tid >> 6;          // wave in [0,4)
    const int lane = tid & 63;
    const int quad = lane >> 4;
    const int nib = lane & 15;
    const int b0 = blockIdx.x * 32;
    const int TFUT = *futlen;
    const int jh[2] = {16 * w + nib, 16 * w + nib + 64};

    // zero-init LDS state. h1: BOTH parities (pipelined L1(0) reads h1[1]).
    h0buf[0][tid] = (short8)0;
    h0buf[0][256 + tid] = (short8)0;
    h1buf[0][tid] = (short8)0;
    h1buf[0][256 + tid] = (short8)0;
    h1buf[1][tid] = (short8)0;
    h1buf[1][256 + tid] = (short8)0;
    ((short8*)xbuf)[tid] = (short8)0;  // 256 slots = both parities
    if (tid < 64) ybuf[tid] = 0.0f;
    for (int i = tid; i < 32 * 132; i += 256) {
        cbuf0[i] = 0.0f;
        cbuf1[i] = 0.0f;
    }
    __syncthreads();  // zero-init visible before initial staging writes

    // stage x(t=0) into xbuf[0]
    if (tid < 64) {
        int m = tid & 31, part = tid >> 5;
        const float* hp = hist + ((size_t)((b0 + m) * 20 + 0)) * 10;
        float v[8];
        if (part == 0) {
#pragma unroll
            for (int i = 0; i < 8; ++i) v[i] = hp[i];
        } else {
            v[0] = hp[8]; v[1] = hp[9];
#pragma unroll
            for (int i = 2; i < 8; ++i) v[i] = 0.0f;
        }
        short8 pk;
#pragma unroll
        for (int i = 0; i < 8; ++i) pk[i] = (short)f2bf(v[i]);
        xbuf[0][m * 4 + (part ^ (m & 3))] = pk;
    }

    // per-jj base byte offsets (q-stride is the compile-time 128*RB in ldb4q)
    unsigned e0b[2], e1b[2], d0b[2];
#pragma unroll
    for (int jj = 0; jj < 2; ++jj) {
        unsigned rr = 64u * jj + 16u * w + nib;
        e0b[jj] = rr * 320u + quad * 16u;
        e1b[jj] = rr * 512u + quad * 16u;
        d0b[jj] = rr * 256u + quad * 16u;
    }
    int p0 = 0, p1 = 0, px = 0;
    __syncthreads();

    // ================= ENCODER: 21 layer-pipelined windows =================
    // window wdw: L0(wdw) [wdw<20] + L1(wdw-1) [wdw>=1]; ONE barrier.
    // jj-halves sequential: mma(jj) -> cell(jj). All mma reads old parity;
    // cells write new parity -> no hazards, live acc stays 32 f32.
#pragma unroll 1
    for (int wdw = 0; wdw < 21; ++wdw) {
        if (wdw < 20) {
            // ---- L0(wdw): gates = x@Wih0^T + h0@Whh0^T; fused cell ----
            unsigned short* hdst = (unsigned short*)h0buf[p0 ^ 1];
#pragma unroll 1
            for (int jj = 0; jj < 2; ++jj) {
                float4v acc[4][2];
#pragma unroll
                for (int q = 0; q < 4; ++q)
#pragma unroll
                    for (int mt = 0; mt < 2; ++mt) acc[q][mt] = (float4v){0.f, 0.f, 0.f, 0.f};
                // x part (k 0..31) from xbuf[px]
                {
                    const short8* xb = xbuf[px];
                    int sxx = (quad ^ (nib & 3)) + nib * 4;
                    short8 a0 = xb[sxx];
                    short8 a1 = xb[64 + sxx];
                    short8 b[4];
                    ldb4q<320>(We0, e0b[jj], 0, b);
#pragma unroll
                    for (int q = 0; q < 4; ++q) {
                        acc[q][0] = MFMA16(a0, b[q], acc[q][0]);
                        acc[q][1] = MFMA16(a1, b[q], acc[q][1]);
                    }
                }
                // h part (W k 32..159, bytes 64..) from h0buf[p0]
                mma_seq<320, 4>(acc, h0buf[p0], We0, e0b[jj], 64, nib, quad);
                cell_upd<false>(acc, jh[jj], bsT + 0 * 512, cbuf0, hdst, nullptr, nullptr, quad);
            }
        }

        // stage x(wdw+1) into xbuf[px^1] (consumed next window after barrier)
        if (tid < 64 && wdw < 19) {
            int m = tid & 31, part = tid >> 5;
            const float* hp = hist + ((size_t)((b0 + m) * 20 + (wdw + 1))) * 10;
            float v[8];
            if (part == 0) {
#pragma unroll
                for (int i = 0; i < 8; ++i) v[i] = hp[i];
            } else {
                v[0] = hp[8]; v[1] = hp[9];
#pragma unroll
                for (int i = 2; i < 8; ++i) v[i] = 0.0f;
            }
            short8 pk;
#pragma unroll
            for (int i = 0; i < 8; ++i) pk[i] = (short)f2bf(v[i]);
            xbuf[px ^ 1][m * 4 + (part ^ (m & 3))] = pk;
        }

        if (wdw >= 1) {
            // ---- L1(wdw-1): gates = h0(wdw-1)@Wih1^T + h1(wdw-2)@Whh1^T ----
            unsigned short* hdst = (unsigned short*)h1buf[p1 ^ 1];
#pragma unroll 1
            for (int jj = 0; jj < 2; ++jj) {
                float4v acc[4][2];
#pragma unroll
                for (int q = 0; q < 4; ++q)
#pragma unroll
                    for (int mt = 0; mt < 2; ++mt) acc[q][mt] = (float4v){0.f, 0.f, 0.f, 0.f};
                mma_seq<512, 4>(acc, h0buf[p0], We1, e1b[jj], 0, nib, quad);
                mma_seq<512, 4>(acc, h1buf[p1], We1, e1b[jj], 256, nib, quad);
                cell_upd<false>(acc, jh[jj], bsT + 1 * 512, cbuf1, hdst, nullptr, nullptr, quad);
            }
        }
        __syncthreads();
        p0 ^= 1; p1 ^= 1; px ^= 1;
    }

    // Parity ledger: h0(19) -> h0buf[0]; h1(19) -> h1buf[1].
    p0 = 0;
    p1 = 1;

    // ================= DECODER =================
    // Per window t: head(t-1) || mma0-jj0 -> A -> cell0-jj0 -> mma0-jj1 ->
    // cell0-jj1 -> B -> [mma1-jj + cell1-jj] -> C.  Epilogue: head(TFUT-1).
#pragma unroll 1
    for (int t = 0; t < TFUT; ++t) {
        // ---- head(t-1) (tid<64, hidden behind mma0) ----
        if (tid < 64 && t >= 1) {
            int m = tid & 31, jj = tid >> 5;
            const short8* hb = h1buf[p1];
            const float4v* hw = (const float4v*)(headW + jj * 128);
            float dot = headB[jj];
            int mk = m & 15;
#pragma unroll
            for (int kc = 0; kc < 16; ++kc) {
                short8 ch = hb[m * 16 + (kc ^ mk)];
                float4v w0 = hw[kc * 2], w1 = hw[kc * 2 + 1];
                dot += bf2f((unsigned short)ch[0]) * w0[0];
                dot += bf2f((unsigned short)ch[1]) * w0[1];
                dot += bf2f((unsigned short)ch[2]) * w0[2];
                dot += bf2f((unsigned short)ch[3]) * w0[3];
                dot += bf2f((unsigned short)ch[4]) * w1[0];
                dot += bf2f((unsigned short)ch[5]) * w1[1];
                dot += bf2f((unsigned short)ch[6]) * w1[2];
                dot += bf2f((unsigned short)ch[7]) * w1[3];
            }
            ybuf[2 * m + jj] = dot;
            out[((size_t)(b0 + m) * TFUT + (t - 1)) * 2 + jj] = dot;
        }

        // ---- dec layer 0: mma0-jj0 -> A -> cell0-jj0 -> mma0-jj1 -> cell0-jj1 ----
        {
            unsigned short* hdst = (unsigned short*)h0buf[p0 ^ 1];
            // jj = 0
            float4v acc[4][2];
#pragma unroll
            for (int q = 0; q < 4; ++q)
#pragma unroll
                for (int mt = 0; mt < 2; ++mt) acc[q][mt] = (float4v){0.f, 0.f, 0.f, 0.f};
            mma_seq<256, 4>(acc, h0buf[p0], Wd0, d0b[0], 0, nib, quad);
            __syncthreads();  // A: ybuf(t-1) visible
            cell_upd<true>(acc, jh[0], bsT + 2 * 512, cbuf0, hdst, ybuf, wyT, quad);
            // jj = 1 (reads old parity h0buf[p0]; cell above wrote p0^1 -> safe)
#pragma unroll
            for (int q = 0; q < 4; ++q)
#pragma unroll
                for (int mt = 0; mt < 2; ++mt) acc[q][mt] = (float4v){0.f, 0.f, 0.f, 0.f};
            mma_seq<256, 4>(acc, h0buf[p0], Wd0, d0b[1], 0, nib, quad);
            cell_upd<true>(acc, jh[1], bsT + 2 * 512, cbuf0, hdst, ybuf, wyT, quad);
        }
        __syncthreads();  // B: h0 new visible

        // ---- dec layer 1 (reads NEW h0 + old h1); fused cell ----
        {
            unsigned short* hdst = (unsigned short*)h1buf[p1 ^ 1];
#pragma unroll 1
            for (int jj = 0; jj < 2; ++jj) {
                float4v acc[4][2];
#pragma unroll
                for (int q = 0; q < 4; ++q)
#pragma unroll
                    for (int mt = 0; mt < 2; ++mt) acc[q][mt] = (float4v){0.f, 0.f, 0.f, 0.f};
                mma_seq<512, 4>(acc, h0buf[p0 ^ 1], Wd1, e1b[jj], 0, nib, quad);
                mma_seq<512, 4>(acc, h1buf[p1], Wd1, e1b[jj], 256, nib, quad);
                cell_upd<false>(acc, jh[jj], bsT + 3 * 512, cbuf1, hdst, nullptr, nullptr, quad);
            }
        }
        __syncthreads();  // C: h1 new visible (next window's head reads it)
        p0 ^= 1; p1 ^= 1;
    }

    // ---- epilogue: head(TFUT-1) ----
    if (tid < 64) {
        int m = tid & 31, jj = tid >> 5;
        const short8* hb = h1buf[p1];
        const float4v* hw = (const float4v*)(headW + jj * 128);
        float dot = headB[jj];
        int mk = m & 15;
#pragma unroll
        for (int kc = 0; kc < 16; ++kc) {
            short8 ch = hb[m * 16 + (kc ^ mk)];
            float4v w0 = hw[kc * 2], w1 = hw[kc * 2 + 1];
            dot += bf2f((unsigned short)ch[0]) * w0[0];
            dot += bf2f((unsigned short)ch[1]) * w0[1];
            dot += bf2f((unsigned short)ch[2]) * w0[2];
            dot += bf2f((unsigned short)ch[3]) * w0[3];
            dot += bf2f((unsigned short)ch[4]) * w1[0];
            dot += bf2f((unsigned short)ch[5]) * w1[1];
            dot += bf2f((unsigned short)ch[6]) * w1[2];
            dot += bf2f((unsigned short)ch[7]) * w1[3];
        }
        out[((size_t)(b0 + m) * TFUT + (TFUT - 1)) * 2 + jj] = dot;
    }
}

extern "C" void kernel_launch(void* const* d_in, const int* in_sizes, int n_in,
                              void* d_out, int out_size, void* d_ws, size_t ws_size,
                              hipStream_t stream)
{
    const float* hist   = (const float*)d_in[0];
    const float* eWih0  = (const float*)d_in[1];
    const float* eWhh0  = (const float*)d_in[2];
    const float* ebih0  = (const float*)d_in[3];
    const float* ebhh0  = (const float*)d_in[4];
    const float* eWih1  = (const float*)d_in[5];
    const float* eWhh1  = (const float*)d_in[6];
    const float* ebih1  = (const float*)d_in[7];
    const float* ebhh1  = (const float*)d_in[8];
    const float* dWih0  = (const float*)d_in[9];
    const float* dWhh0  = (const float*)d_in[10];
    const float* dbih0  = (const float*)d_in[11];
    const float* dbhh0  = (const float*)d_in[12];
    const float* dWih1  = (const float*)d_in[13];
    const float* dWhh1  = (const float*)d_in[14];
    const float* dbih1  = (const float*)d_in[15];
    const float* dbhh1  = (const float*)d_in[16];
    const float* headW  = (const float*)d_in[17];
    const float* headB  = (const float*)d_in[18];
    const int*   futlen = (const int*)d_in[19];

    // weights 409600 bf16 + bsT 2048 f32 + wyT 1024 f32 -> 412672 work items
    prep_kernel<<<1612, 256, 0, stream>>>(eWih0, eWhh0, ebih0, ebhh0,
                                          eWih1, eWhh1, ebih1, ebhh1,
                                          dWih0, dWhh0, dbih0, dbhh0,
                                          dWih1, dWhh1, dbih1, dbhh1, d_ws);

    lstm_main<<<512, 256, 0, stream>>>(hist, headW, headB, futlen,
                                       d_ws, (float*)d_out);
}